// Round 3
// baseline (1228.461 us; speedup 1.0000x reference)
//
#include <hip/hip_runtime.h>
#include <hip/hip_bf16.h>

#define NFEAT 128
#define NHID  64
#define NCLASS 40
#define NLAYERS 4

// ---------------- CSR build ----------------

// degree counts only — fire-and-forget atomics, no return values
__global__ void count_edges_k(const int* __restrict__ ei, int E,
                              int* __restrict__ cnt_row, int* __restrict__ cnt_col) {
    int e = blockIdx.x * blockDim.x + threadIdx.x;
    if (e >= E) return;
    atomicAdd(&cnt_row[ei[e]], 1);      // out-degree (gamma denom)
    atomicAdd(&cnt_col[ei[E + e]], 1);  // in-degree
}

__global__ void dinv_k(const int* __restrict__ cnt_col, float* __restrict__ dinv, int n) {
    int v = blockIdx.x * blockDim.x + threadIdx.x;
    if (v >= n) return;
    dinv[v] = 1.0f / sqrtf((float)(cnt_col[v] + 1));   // deg incl. self loop
}

// block-level exclusive scan (1024 elems / block), emits block sums
__global__ void scanA_k(const int* __restrict__ cnt, int* __restrict__ off,
                        int* __restrict__ bsum, int n) {
    __shared__ int t[1024];
    int i = blockIdx.x * 1024 + threadIdx.x;
    int x = (i < n) ? cnt[i] : 0;
    t[threadIdx.x] = x;
    __syncthreads();
    for (int d = 1; d < 1024; d <<= 1) {
        int y = (threadIdx.x >= (unsigned)d) ? t[threadIdx.x - d] : 0;
        __syncthreads();
        t[threadIdx.x] += y;
        __syncthreads();
    }
    if (i < n) off[i] = t[threadIdx.x] - x;   // exclusive
    if (threadIdx.x == 1023) bsum[blockIdx.x] = t[1023];
}

__global__ void scanB_k(int* __restrict__ bsum, int nb) {
    __shared__ int t[1024];
    int x = (threadIdx.x < (unsigned)nb) ? bsum[threadIdx.x] : 0;
    t[threadIdx.x] = x;
    __syncthreads();
    for (int d = 1; d < 1024; d <<= 1) {
        int y = (threadIdx.x >= (unsigned)d) ? t[threadIdx.x - d] : 0;
        __syncthreads();
        t[threadIdx.x] += y;
        __syncthreads();
    }
    if (threadIdx.x < (unsigned)nb) bsum[threadIdx.x] = t[threadIdx.x] - x;
}

__global__ void scanC_k(int* __restrict__ off, const int* __restrict__ bsum,
                        int* __restrict__ cur, int n, int total) {
    int i = blockIdx.x * 1024 + threadIdx.x;
    if (i < n) {
        int o = off[i] + bsum[blockIdx.x];
        off[i] = o;
        cur[i] = o;
    }
    if (i == 0) off[n] = total;
}

// cursor-atomic fill, 4 edges/thread for atomic-latency overlap; csr entry = src idx (4B)
__global__ void fill_k(const int* __restrict__ ei, int E,
                       int* __restrict__ cur, int* __restrict__ csr) {
    int t = blockIdx.x * blockDim.x + threadIdx.x;
    int base = t * 4;
    if (base >= E) return;
    if (base + 4 <= E) {
        int4 r4 = *reinterpret_cast<const int4*>(ei + base);
        int4 c4 = *reinterpret_cast<const int4*>(ei + E + base);
        int p0 = atomicAdd(&cur[c4.x], 1);
        int p1 = atomicAdd(&cur[c4.y], 1);
        int p2 = atomicAdd(&cur[c4.z], 1);
        int p3 = atomicAdd(&cur[c4.w], 1);
        csr[p0] = r4.x;
        csr[p1] = r4.y;
        csr[p2] = r4.z;
        csr[p3] = r4.w;
    } else {
        for (int e = base; e < E; ++e) {
            int p = atomicAdd(&cur[ei[E + e]], 1);
            csr[p] = ei[e];
        }
    }
}

// ---------------- dense, acc-major: out[v,:] = A[v,:] @ W[M,K]^T (+b) ----------------
// acc[M] persistent in VGPRs (M<=64 -> no spill); A-row streamed as float4;
// W/b reads are wave-uniform (scalar loads).

template<int K, int M, bool RELU, bool BIAS>
__global__ void dense_k(const float* __restrict__ A, const float* __restrict__ W,
                        const float* __restrict__ b, float* __restrict__ out, int n) {
    int v = blockIdx.x * blockDim.x + threadIdx.x;
    if (v >= n) return;
    float acc[M];
#pragma unroll
    for (int m = 0; m < M; ++m) acc[m] = BIAS ? b[m] : 0.f;
    const float4* ap = reinterpret_cast<const float4*>(A + (size_t)v * K);
#pragma unroll 1
    for (int kb = 0; kb < K / 4; ++kb) {
        float4 a4 = ap[kb];
#pragma unroll
        for (int m = 0; m < M; ++m) {
            const float* wr = W + (size_t)m * K + kb * 4;
            acc[m] = fmaf(a4.x, wr[0], acc[m]);
            acc[m] = fmaf(a4.y, wr[1], acc[m]);
            acc[m] = fmaf(a4.z, wr[2], acc[m]);
            acc[m] = fmaf(a4.w, wr[3], acc[m]);
        }
    }
    float4* op = reinterpret_cast<float4*>(out + (size_t)v * M);
#pragma unroll
    for (int m = 0; m < M; m += 4) {
        float4 o;
        o.x = RELU ? fmaxf(acc[m + 0], 0.f) : acc[m + 0];
        o.y = RELU ? fmaxf(acc[m + 1], 0.f) : acc[m + 1];
        o.z = RELU ? fmaxf(acc[m + 2], 0.f) : acc[m + 2];
        o.w = RELU ? fmaxf(acc[m + 3], 0.f) : acc[m + 3];
        op[m >> 2] = o;
    }
}

// ---------------- fused gather: agg (in-edges of v) + gamma scatter ----------------
// wave per node; 4 groups of 16 lanes; each group one edge at a time, full X row
// as float4/lane. Computes:
//   pre[v] = dinv[v] * sum_in(dinv[src]*X[src]) + dinv[v]^2 * X[v]
//   gs[src] += ||X[src]-X[v]||^2   (no-return float atomic)
__global__ void gather_k(const float* __restrict__ X, const int* __restrict__ csr,
                         const int* __restrict__ col_off, const float* __restrict__ dinv,
                         float* __restrict__ pre, float* __restrict__ gs, int n) {
    int v = blockIdx.x * 4 + (threadIdx.x >> 6);
    if (v >= n) return;
    int lane = threadIdx.x & 63;
    int grp = lane >> 4;
    int sub = lane & 15;

    float4 xv = reinterpret_cast<const float4*>(X + (size_t)v * NHID)[sub];
    int beg = col_off[v], end = col_off[v + 1];

    float4 acc = make_float4(0.f, 0.f, 0.f, 0.f);
    for (int e = beg + grp; e < end; e += 4) {
        int s = csr[e];
        float w = dinv[s];   // broadcast load (all 16 lanes same addr), L2-resident
        float4 xs = reinterpret_cast<const float4*>(X + (size_t)s * NHID)[sub];
        acc.x = fmaf(w, xs.x, acc.x);
        acc.y = fmaf(w, xs.y, acc.y);
        acc.z = fmaf(w, xs.z, acc.z);
        acc.w = fmaf(w, xs.w, acc.w);
        float dx = xs.x - xv.x;
        float part = dx * dx;
        dx = xs.y - xv.y; part = fmaf(dx, dx, part);
        dx = xs.z - xv.z; part = fmaf(dx, dx, part);
        dx = xs.w - xv.w; part = fmaf(dx, dx, part);
#pragma unroll
        for (int m = 1; m <= 8; m <<= 1) part += __shfl_xor(part, m, 64);
        if (sub == 0) atomicAdd(&gs[s], part);
    }
#pragma unroll
    for (int m = 16; m <= 32; m <<= 1) {
        acc.x += __shfl_xor(acc.x, m, 64);
        acc.y += __shfl_xor(acc.y, m, 64);
        acc.z += __shfl_xor(acc.z, m, 64);
        acc.w += __shfl_xor(acc.w, m, 64);
    }
    if (grp == 0) {
        float dv = dinv[v];
        float dv2 = dv * dv;
        float4 o;
        o.x = fmaf(dv, acc.x, dv2 * xv.x);
        o.y = fmaf(dv, acc.y, dv2 * xv.y);
        o.z = fmaf(dv, acc.z, dv2 * xv.z);
        o.w = fmaf(dv, acc.w, dv2 * xv.w);
        reinterpret_cast<float4*>(pre + (size_t)v * NHID)[sub] = o;
    }
}

// ---------------- fused per-layer epilogue ----------------
// t = relu(pre @ W^T + b); g = tanh(gs/max(outdeg,1));
// X = (X + g*(t + skip)) / (1 + 2g);  gs = 0 for next layer
__global__ void update_k(float* __restrict__ X, const float* __restrict__ pre,
                         const float* __restrict__ skip, const float* __restrict__ W,
                         const float* __restrict__ b, float* __restrict__ gs,
                         const int* __restrict__ cnt_row, int n) {
    int v = blockIdx.x * blockDim.x + threadIdx.x;
    if (v >= n) return;
    float acc[NHID];
#pragma unroll
    for (int m = 0; m < NHID; ++m) acc[m] = b[m];
    const float4* ap = reinterpret_cast<const float4*>(pre + (size_t)v * NHID);
#pragma unroll 1
    for (int kb = 0; kb < NHID / 4; ++kb) {
        float4 a4 = ap[kb];
#pragma unroll
        for (int m = 0; m < NHID; ++m) {
            const float* wr = W + (size_t)m * NHID + kb * 4;
            acc[m] = fmaf(a4.x, wr[0], acc[m]);
            acc[m] = fmaf(a4.y, wr[1], acc[m]);
            acc[m] = fmaf(a4.z, wr[2], acc[m]);
            acc[m] = fmaf(a4.w, wr[3], acc[m]);
        }
    }
    float gv = tanhf(gs[v] / fmaxf((float)cnt_row[v], 1.f));
    gs[v] = 0.f;
    float inv = 1.0f / (1.0f + 2.0f * gv);

    float4* Xp = reinterpret_cast<float4*>(X + (size_t)v * NHID);
    const float4* Sp = reinterpret_cast<const float4*>(skip + (size_t)v * NHID);
#pragma unroll
    for (int m = 0; m < NHID; m += 4) {
        float t0 = fmaxf(acc[m + 0], 0.f);
        float t1 = fmaxf(acc[m + 1], 0.f);
        float t2 = fmaxf(acc[m + 2], 0.f);
        float t3 = fmaxf(acc[m + 3], 0.f);
        float4 x4 = Xp[m >> 2];
        float4 s4 = Sp[m >> 2];
        float4 o;
        o.x = (x4.x + gv * (t0 + s4.x)) * inv;
        o.y = (x4.y + gv * (t1 + s4.y)) * inv;
        o.z = (x4.z + gv * (t2 + s4.z)) * inv;
        o.w = (x4.w + gv * (t3 + s4.w)) * inv;
        Xp[m >> 2] = o;
    }
}

// ---------------- launch ----------------

extern "C" void kernel_launch(void* const* d_in, const int* in_sizes, int n_in,
                              void* d_out, int out_size, void* d_ws, size_t ws_size,
                              hipStream_t stream) {
    const float* x      = (const float*)d_in[0];
    const int*   ei     = (const int*)  d_in[1];
    const float* enc_W  = (const float*)d_in[2];
    const float* enc_b  = (const float*)d_in[3];
    const float* conv_W = (const float*)d_in[4];
    const float* conv_b = (const float*)d_in[5];
    const float* W_skip = (const float*)d_in[6];
    const float* dec_W  = (const float*)d_in[7];
    const float* dec_b  = (const float*)d_in[8];

    const int n = in_sizes[0] / NFEAT;
    const int E = in_sizes[1] / 2;

    char* ws = (char*)d_ws;
    auto alloc = [&](size_t bytes) {
        char* p = ws;
        ws += (bytes + 255) & ~(size_t)255;
        return p;
    };

    float* X    = (float*)alloc((size_t)n * NHID * 4);
    float* pre  = (float*)alloc((size_t)n * NHID * 4);
    float* skip = (float*)alloc((size_t)n * NHID * 4);
    float* gs   = (float*)alloc((size_t)n * 4);
    float* dinv = (float*)alloc((size_t)n * 4);
    int* cnt_row = (int*)alloc((size_t)n * 4);
    int* cnt_col = (int*)alloc((size_t)n * 4);
    int* col_off = (int*)alloc((size_t)(n + 1) * 4);
    int* cur     = (int*)alloc((size_t)n * 4);
    int* bsc     = (int*)alloc(1024 * 4);
    int* csr     = (int*)alloc((size_t)E * 4);

    hipMemsetAsync(cnt_row, 0, (size_t)n * 4, stream);
    hipMemsetAsync(cnt_col, 0, (size_t)n * 4, stream);
    hipMemsetAsync(gs, 0, (size_t)n * 4, stream);

    count_edges_k<<<(E + 255) / 256, 256, 0, stream>>>(ei, E, cnt_row, cnt_col);
    dinv_k<<<(n + 255) / 256, 256, 0, stream>>>(cnt_col, dinv, n);

    int nb = (n + 1023) / 1024;
    scanA_k<<<nb, 1024, 0, stream>>>(cnt_col, col_off, bsc, n);
    scanB_k<<<1, 1024, 0, stream>>>(bsc, nb);
    scanC_k<<<nb, 1024, 0, stream>>>(col_off, bsc, cur, n, E);
    fill_k<<<(E / 4 + 255) / 256, 256, 0, stream>>>(ei, E, cur, csr);

    // encoder: X = relu(x @ enc_W^T + enc_b)
    dense_k<NFEAT, NHID, true, true><<<(n + 255) / 256, 256, 0, stream>>>(x, enc_W, enc_b, X, n);
    // skip_val = X_init @ W_skip^T
    dense_k<NHID, NHID, false, false><<<(n + 255) / 256, 256, 0, stream>>>(X, W_skip, nullptr, skip, n);

    for (int l = 0; l < NLAYERS; ++l) {
        gather_k<<<(n + 3) / 4, 256, 0, stream>>>(X, csr, col_off, dinv, pre, gs, n);
        update_k<<<(n + 255) / 256, 256, 0, stream>>>(X, pre, skip, conv_W, conv_b, gs, cnt_row, n);
    }

    // decode: out = X @ dec_W^T + dec_b
    dense_k<NHID, NCLASS, false, true><<<(n + 255) / 256, 256, 0, stream>>>(X, dec_W, dec_b, (float*)d_out, n);
}

// Round 4
// 1051.556 us; speedup vs baseline: 1.1682x; 1.1682x over previous
//
#include <hip/hip_runtime.h>
#include <hip/hip_bf16.h>

#define NFEAT 128
#define NHID  64
#define NCLASS 40
#define NLAYERS 4

// ---------------- CSR build ----------------

// in-degree counts only — fire-and-forget atomics, 4 edges/thread
__global__ void count_in_k(const int* __restrict__ ei, int E, int* __restrict__ cnt_col) {
    int t = blockIdx.x * blockDim.x + threadIdx.x;
    int base = t * 4;
    if (base >= E) return;
    if (base + 4 <= E) {
        int4 c4 = *reinterpret_cast<const int4*>(ei + E + base);
        atomicAdd(&cnt_col[c4.x], 1);
        atomicAdd(&cnt_col[c4.y], 1);
        atomicAdd(&cnt_col[c4.z], 1);
        atomicAdd(&cnt_col[c4.w], 1);
    } else {
        for (int e = base; e < E; ++e) atomicAdd(&cnt_col[ei[E + e]], 1);
    }
}

__global__ void dinv_k(const int* __restrict__ cnt_col, float* __restrict__ dinv, int n) {
    int v = blockIdx.x * blockDim.x + threadIdx.x;
    if (v >= n) return;
    dinv[v] = 1.0f / sqrtf((float)(cnt_col[v] + 1));   // deg incl. self loop
}

// block-level exclusive scan (1024 elems / block), emits block sums
__global__ void scanA_k(const int* __restrict__ cnt, int* __restrict__ off,
                        int* __restrict__ bsum, int n) {
    __shared__ int t[1024];
    int i = blockIdx.x * 1024 + threadIdx.x;
    int x = (i < n) ? cnt[i] : 0;
    t[threadIdx.x] = x;
    __syncthreads();
    for (int d = 1; d < 1024; d <<= 1) {
        int y = (threadIdx.x >= (unsigned)d) ? t[threadIdx.x - d] : 0;
        __syncthreads();
        t[threadIdx.x] += y;
        __syncthreads();
    }
    if (i < n) off[i] = t[threadIdx.x] - x;   // exclusive
    if (threadIdx.x == 1023) bsum[blockIdx.x] = t[1023];
}

__global__ void scanB_k(int* __restrict__ bsum, int nb) {
    __shared__ int t[1024];
    int x = (threadIdx.x < (unsigned)nb) ? bsum[threadIdx.x] : 0;
    t[threadIdx.x] = x;
    __syncthreads();
    for (int d = 1; d < 1024; d <<= 1) {
        int y = (threadIdx.x >= (unsigned)d) ? t[threadIdx.x - d] : 0;
        __syncthreads();
        t[threadIdx.x] += y;
        __syncthreads();
    }
    if (threadIdx.x < (unsigned)nb) bsum[threadIdx.x] = t[threadIdx.x] - x;
}

__global__ void scanC_k(int* __restrict__ off, const int* __restrict__ bsum,
                        int* __restrict__ cur, int n, int total) {
    int i = blockIdx.x * 1024 + threadIdx.x;
    if (i < n) {
        int o = off[i] + bsum[blockIdx.x];
        off[i] = o;
        cur[i] = o;
    }
    if (i == 0) off[n] = total;
}

// cursor-atomic fill, 8 edges/thread; also counts out-degree (fire-and-forget)
__global__ void fill_k(const int* __restrict__ ei, int E,
                       int* __restrict__ cur, int* __restrict__ cnt_row,
                       int* __restrict__ csr) {
    int t = blockIdx.x * blockDim.x + threadIdx.x;
    int base = t * 8;
    if (base >= E) return;
    if (base + 8 <= E) {
        int4 rA = *reinterpret_cast<const int4*>(ei + base);
        int4 rB = *reinterpret_cast<const int4*>(ei + base + 4);
        int4 cA = *reinterpret_cast<const int4*>(ei + E + base);
        int4 cB = *reinterpret_cast<const int4*>(ei + E + base + 4);
        int p0 = atomicAdd(&cur[cA.x], 1);
        int p1 = atomicAdd(&cur[cA.y], 1);
        int p2 = atomicAdd(&cur[cA.z], 1);
        int p3 = atomicAdd(&cur[cA.w], 1);
        int p4 = atomicAdd(&cur[cB.x], 1);
        int p5 = atomicAdd(&cur[cB.y], 1);
        int p6 = atomicAdd(&cur[cB.z], 1);
        int p7 = atomicAdd(&cur[cB.w], 1);
        atomicAdd(&cnt_row[rA.x], 1);
        atomicAdd(&cnt_row[rA.y], 1);
        atomicAdd(&cnt_row[rA.z], 1);
        atomicAdd(&cnt_row[rA.w], 1);
        atomicAdd(&cnt_row[rB.x], 1);
        atomicAdd(&cnt_row[rB.y], 1);
        atomicAdd(&cnt_row[rB.z], 1);
        atomicAdd(&cnt_row[rB.w], 1);
        csr[p0] = rA.x;
        csr[p1] = rA.y;
        csr[p2] = rA.z;
        csr[p3] = rA.w;
        csr[p4] = rB.x;
        csr[p5] = rB.y;
        csr[p6] = rB.z;
        csr[p7] = rB.w;
    } else {
        for (int e = base; e < E; ++e) {
            int r = ei[e];
            int p = atomicAdd(&cur[ei[E + e]], 1);
            atomicAdd(&cnt_row[r], 1);
            csr[p] = r;
        }
    }
}

// ---------------- dense K=64 (R1-proven): preload a[K], m-chunks of 4 accs ----------------

template<int K, int M, bool RELU, bool BIAS>
__global__ void dense_small_k(const float* __restrict__ A, const float* __restrict__ W,
                              const float* __restrict__ b, float* __restrict__ out, int n) {
    int v = blockIdx.x * blockDim.x + threadIdx.x;
    if (v >= n) return;
    float a[K];
    const float4* ap = reinterpret_cast<const float4*>(A + (size_t)v * K);
#pragma unroll
    for (int k = 0; k < K / 4; ++k) {
        float4 t = ap[k];
        a[4 * k + 0] = t.x; a[4 * k + 1] = t.y; a[4 * k + 2] = t.z; a[4 * k + 3] = t.w;
    }
    float4* op = reinterpret_cast<float4*>(out + (size_t)v * M);
#pragma unroll 1
    for (int m = 0; m < M; m += 4) {
        float acc0 = BIAS ? b[m + 0] : 0.f;
        float acc1 = BIAS ? b[m + 1] : 0.f;
        float acc2 = BIAS ? b[m + 2] : 0.f;
        float acc3 = BIAS ? b[m + 3] : 0.f;
#pragma unroll
        for (int k = 0; k < K; ++k) {
            float av = a[k];
            acc0 = fmaf(av, W[(m + 0) * K + k], acc0);
            acc1 = fmaf(av, W[(m + 1) * K + k], acc1);
            acc2 = fmaf(av, W[(m + 2) * K + k], acc2);
            acc3 = fmaf(av, W[(m + 3) * K + k], acc3);
        }
        if (RELU) {
            acc0 = fmaxf(acc0, 0.f); acc1 = fmaxf(acc1, 0.f);
            acc2 = fmaxf(acc2, 0.f); acc3 = fmaxf(acc3, 0.f);
        }
        float4 o; o.x = acc0; o.y = acc1; o.z = acc2; o.w = acc3;
        op[m >> 2] = o;
    }
}

// ---------------- encoder (K=128): 2 passes of acc[32], stream A-row each pass ----------------

template<int K, int M, int MC>
__global__ void dense_enc_k(const float* __restrict__ A, const float* __restrict__ W,
                            const float* __restrict__ b, float* __restrict__ out, int n) {
    int v = blockIdx.x * blockDim.x + threadIdx.x;
    if (v >= n) return;
    const float4* ap = reinterpret_cast<const float4*>(A + (size_t)v * K);
    float4* op = reinterpret_cast<float4*>(out + (size_t)v * M);
#pragma unroll 1
    for (int mc = 0; mc < M; mc += MC) {
        float acc[MC];
#pragma unroll
        for (int m = 0; m < MC; ++m) acc[m] = b[mc + m];
#pragma unroll 1
        for (int kb = 0; kb < K / 4; ++kb) {
            float4 a4 = ap[kb];
#pragma unroll
            for (int m = 0; m < MC; ++m) {
                const float* wr = W + (size_t)(mc + m) * K + kb * 4;
                acc[m] = fmaf(a4.x, wr[0], acc[m]);
                acc[m] = fmaf(a4.y, wr[1], acc[m]);
                acc[m] = fmaf(a4.z, wr[2], acc[m]);
                acc[m] = fmaf(a4.w, wr[3], acc[m]);
            }
        }
#pragma unroll
        for (int m = 0; m < MC; m += 4) {
            float4 o;
            o.x = fmaxf(acc[m + 0], 0.f);
            o.y = fmaxf(acc[m + 1], 0.f);
            o.z = fmaxf(acc[m + 2], 0.f);
            o.w = fmaxf(acc[m + 3], 0.f);
            op[(mc + m) >> 2] = o;
        }
    }
}

// ---------------- fused gather: agg (in-edges of v) + gamma scatter ----------------
__global__ void gather_k(const float* __restrict__ X, const int* __restrict__ csr,
                         const int* __restrict__ col_off, const float* __restrict__ dinv,
                         float* __restrict__ pre, float* __restrict__ gs, int n) {
    int v = blockIdx.x * 4 + (threadIdx.x >> 6);
    if (v >= n) return;
    int lane = threadIdx.x & 63;
    int grp = lane >> 4;
    int sub = lane & 15;

    float4 xv = reinterpret_cast<const float4*>(X + (size_t)v * NHID)[sub];
    int beg = col_off[v], end = col_off[v + 1];

    float4 acc = make_float4(0.f, 0.f, 0.f, 0.f);
    for (int e = beg + grp; e < end; e += 4) {
        int s = csr[e];
        float w = dinv[s];
        float4 xs = reinterpret_cast<const float4*>(X + (size_t)s * NHID)[sub];
        acc.x = fmaf(w, xs.x, acc.x);
        acc.y = fmaf(w, xs.y, acc.y);
        acc.z = fmaf(w, xs.z, acc.z);
        acc.w = fmaf(w, xs.w, acc.w);
        float dx = xs.x - xv.x;
        float part = dx * dx;
        dx = xs.y - xv.y; part = fmaf(dx, dx, part);
        dx = xs.z - xv.z; part = fmaf(dx, dx, part);
        dx = xs.w - xv.w; part = fmaf(dx, dx, part);
#pragma unroll
        for (int m = 1; m <= 8; m <<= 1) part += __shfl_xor(part, m, 64);
        if (sub == 0) atomicAdd(&gs[s], part);
    }
#pragma unroll
    for (int m = 16; m <= 32; m <<= 1) {
        acc.x += __shfl_xor(acc.x, m, 64);
        acc.y += __shfl_xor(acc.y, m, 64);
        acc.z += __shfl_xor(acc.z, m, 64);
        acc.w += __shfl_xor(acc.w, m, 64);
    }
    if (grp == 0) {
        float dv = dinv[v];
        float dv2 = dv * dv;
        float4 o;
        o.x = fmaf(dv, acc.x, dv2 * xv.x);
        o.y = fmaf(dv, acc.y, dv2 * xv.y);
        o.z = fmaf(dv, acc.z, dv2 * xv.z);
        o.w = fmaf(dv, acc.w, dv2 * xv.w);
        reinterpret_cast<float4*>(pre + (size_t)v * NHID)[sub] = o;
    }
}

// ---------------- fused per-layer epilogue (R1-proven structure) ----------------
// t = relu(pre @ W^T + b); g = tanh(gs/max(outdeg,1));
// X = (X + g*(t + skip)) / (1 + 2g);  gs = 0 for next layer
__global__ void update_k(float* __restrict__ X, const float* __restrict__ pre,
                         const float* __restrict__ skip, const float* __restrict__ W,
                         const float* __restrict__ b, float* __restrict__ gs,
                         const int* __restrict__ cnt_row, int n) {
    int v = blockIdx.x * blockDim.x + threadIdx.x;
    if (v >= n) return;
    float a[NHID];
    const float4* ap = reinterpret_cast<const float4*>(pre + (size_t)v * NHID);
#pragma unroll
    for (int k = 0; k < NHID / 4; ++k) {
        float4 t = ap[k];
        a[4 * k + 0] = t.x; a[4 * k + 1] = t.y; a[4 * k + 2] = t.z; a[4 * k + 3] = t.w;
    }
    float gv = tanhf(gs[v] / fmaxf((float)cnt_row[v], 1.f));
    gs[v] = 0.f;
    float inv = 1.0f / (1.0f + 2.0f * gv);

    float4* Xp = reinterpret_cast<float4*>(X + (size_t)v * NHID);
    const float4* Sp = reinterpret_cast<const float4*>(skip + (size_t)v * NHID);
#pragma unroll 1
    for (int m = 0; m < NHID; m += 4) {
        float t0 = b[m + 0], t1 = b[m + 1], t2 = b[m + 2], t3 = b[m + 3];
#pragma unroll
        for (int k = 0; k < NHID; ++k) {
            float av = a[k];
            t0 = fmaf(av, W[(m + 0) * NHID + k], t0);
            t1 = fmaf(av, W[(m + 1) * NHID + k], t1);
            t2 = fmaf(av, W[(m + 2) * NHID + k], t2);
            t3 = fmaf(av, W[(m + 3) * NHID + k], t3);
        }
        t0 = fmaxf(t0, 0.f); t1 = fmaxf(t1, 0.f);
        t2 = fmaxf(t2, 0.f); t3 = fmaxf(t3, 0.f);
        float4 x4 = Xp[m >> 2];
        float4 s4 = Sp[m >> 2];
        float4 o;
        o.x = (x4.x + gv * (t0 + s4.x)) * inv;
        o.y = (x4.y + gv * (t1 + s4.y)) * inv;
        o.z = (x4.z + gv * (t2 + s4.z)) * inv;
        o.w = (x4.w + gv * (t3 + s4.w)) * inv;
        Xp[m >> 2] = o;
    }
}

// ---------------- launch ----------------

extern "C" void kernel_launch(void* const* d_in, const int* in_sizes, int n_in,
                              void* d_out, int out_size, void* d_ws, size_t ws_size,
                              hipStream_t stream) {
    const float* x      = (const float*)d_in[0];
    const int*   ei     = (const int*)  d_in[1];
    const float* enc_W  = (const float*)d_in[2];
    const float* enc_b  = (const float*)d_in[3];
    const float* conv_W = (const float*)d_in[4];
    const float* conv_b = (const float*)d_in[5];
    const float* W_skip = (const float*)d_in[6];
    const float* dec_W  = (const float*)d_in[7];
    const float* dec_b  = (const float*)d_in[8];

    const int n = in_sizes[0] / NFEAT;
    const int E = in_sizes[1] / 2;

    char* ws = (char*)d_ws;
    auto alloc = [&](size_t bytes) {
        char* p = ws;
        ws += (bytes + 255) & ~(size_t)255;
        return p;
    };

    float* X    = (float*)alloc((size_t)n * NHID * 4);
    float* pre  = (float*)alloc((size_t)n * NHID * 4);
    float* skip = (float*)alloc((size_t)n * NHID * 4);
    float* gs   = (float*)alloc((size_t)n * 4);
    float* dinv = (float*)alloc((size_t)n * 4);
    int* cnt_row = (int*)alloc((size_t)n * 4);
    int* cnt_col = (int*)alloc((size_t)n * 4);
    int* col_off = (int*)alloc((size_t)(n + 1) * 4);
    int* cur     = (int*)alloc((size_t)n * 4);
    int* bsc     = (int*)alloc(1024 * 4);
    int* csr     = (int*)alloc((size_t)E * 4);

    hipMemsetAsync(cnt_row, 0, (size_t)n * 4, stream);
    hipMemsetAsync(cnt_col, 0, (size_t)n * 4, stream);
    hipMemsetAsync(gs, 0, (size_t)n * 4, stream);

    count_in_k<<<(E / 4 + 255) / 256, 256, 0, stream>>>(ei, E, cnt_col);
    dinv_k<<<(n + 255) / 256, 256, 0, stream>>>(cnt_col, dinv, n);

    int nb = (n + 1023) / 1024;
    scanA_k<<<nb, 1024, 0, stream>>>(cnt_col, col_off, bsc, n);
    scanB_k<<<1, 1024, 0, stream>>>(bsc, nb);
    scanC_k<<<nb, 1024, 0, stream>>>(col_off, bsc, cur, n, E);
    fill_k<<<(E / 8 + 255) / 256, 256, 0, stream>>>(ei, E, cur, cnt_row, csr);

    // encoder: X = relu(x @ enc_W^T + enc_b)
    dense_enc_k<NFEAT, NHID, 32><<<(n + 255) / 256, 256, 0, stream>>>(x, enc_W, enc_b, X, n);
    // skip_val = X_init @ W_skip^T
    dense_small_k<NHID, NHID, false, false><<<(n + 255) / 256, 256, 0, stream>>>(X, W_skip, nullptr, skip, n);

    for (int l = 0; l < NLAYERS; ++l) {
        gather_k<<<(n + 3) / 4, 256, 0, stream>>>(X, csr, col_off, dinv, pre, gs, n);
        update_k<<<(n + 255) / 256, 256, 0, stream>>>(X, pre, skip, conv_W, conv_b, gs, cnt_row, n);
    }

    // decode: out = X @ dec_W^T + dec_b
    dense_small_k<NHID, NCLASS, false, true><<<(n + 255) / 256, 256, 0, stream>>>(X, dec_W, dec_b, (float*)d_out, n);
}

// Round 5
// 966.426 us; speedup vs baseline: 1.2711x; 1.0881x over previous
//
#include <hip/hip_runtime.h>
#include <hip/hip_bf16.h>

#define NFEAT 128
#define NHID  64
#define NCLASS 40
#define NLAYERS 4

// ---------------- CSR build ----------------

// pass 1: rank via returning atomic (coalesced rank store), out-degree fire-and-forget
__global__ void count_rank_k(const int* __restrict__ ei, int E,
                             int* __restrict__ cnt_col, int* __restrict__ cnt_row,
                             int* __restrict__ rank) {
    int t = blockIdx.x * blockDim.x + threadIdx.x;
    int base = t * 4;
    if (base >= E) return;
    if (base + 4 <= E) {
        int4 c4 = *reinterpret_cast<const int4*>(ei + E + base);
        int4 r4 = *reinterpret_cast<const int4*>(ei + base);
        int4 k4;
        k4.x = atomicAdd(&cnt_col[c4.x], 1);
        k4.y = atomicAdd(&cnt_col[c4.y], 1);
        k4.z = atomicAdd(&cnt_col[c4.z], 1);
        k4.w = atomicAdd(&cnt_col[c4.w], 1);
        atomicAdd(&cnt_row[r4.x], 1);
        atomicAdd(&cnt_row[r4.y], 1);
        atomicAdd(&cnt_row[r4.z], 1);
        atomicAdd(&cnt_row[r4.w], 1);
        *reinterpret_cast<int4*>(rank + base) = k4;
    } else {
        for (int e = base; e < E; ++e) {
            rank[e] = atomicAdd(&cnt_col[ei[E + e]], 1);
            atomicAdd(&cnt_row[ei[e]], 1);
        }
    }
}

// block-level exclusive scan (1024 elems / block), emits block sums; fused dinv
__global__ void scanA_k(const int* __restrict__ cnt, int* __restrict__ off,
                        int* __restrict__ bsum, float* __restrict__ dinv, int n) {
    __shared__ int t[1024];
    int i = blockIdx.x * 1024 + threadIdx.x;
    int x = (i < n) ? cnt[i] : 0;
    if (i < n) dinv[i] = 1.0f / sqrtf((float)(x + 1));   // deg incl. self loop
    t[threadIdx.x] = x;
    __syncthreads();
    for (int d = 1; d < 1024; d <<= 1) {
        int y = (threadIdx.x >= (unsigned)d) ? t[threadIdx.x - d] : 0;
        __syncthreads();
        t[threadIdx.x] += y;
        __syncthreads();
    }
    if (i < n) off[i] = t[threadIdx.x] - x;   // exclusive
    if (threadIdx.x == 1023) bsum[blockIdx.x] = t[1023];
}

__global__ void scanB_k(int* __restrict__ bsum, int nb) {
    __shared__ int t[1024];
    int x = (threadIdx.x < (unsigned)nb) ? bsum[threadIdx.x] : 0;
    t[threadIdx.x] = x;
    __syncthreads();
    for (int d = 1; d < 1024; d <<= 1) {
        int y = (threadIdx.x >= (unsigned)d) ? t[threadIdx.x - d] : 0;
        __syncthreads();
        t[threadIdx.x] += y;
        __syncthreads();
    }
    if (threadIdx.x < (unsigned)nb) bsum[threadIdx.x] = t[threadIdx.x] - x;
}

// finalize offsets; fused gs zero-init
__global__ void scanC_k(int* __restrict__ off, const int* __restrict__ bsum,
                        float* __restrict__ gs, int n, int total) {
    int i = blockIdx.x * 1024 + threadIdx.x;
    if (i < n) {
        off[i] += bsum[blockIdx.x];
        gs[i] = 0.f;
    }
    if (i == 0) off[n] = total;
}

// pass 2: atomic-free scatter, 8 edges/thread, stores fire-and-forget
__global__ void scatter_k(const int* __restrict__ ei, int E,
                          const int* __restrict__ col_off, const int* __restrict__ rank,
                          int* __restrict__ csr) {
    int t = blockIdx.x * blockDim.x + threadIdx.x;
    int base = t * 8;
    if (base >= E) return;
    if (base + 8 <= E) {
        int4 rA = *reinterpret_cast<const int4*>(ei + base);
        int4 rB = *reinterpret_cast<const int4*>(ei + base + 4);
        int4 cA = *reinterpret_cast<const int4*>(ei + E + base);
        int4 cB = *reinterpret_cast<const int4*>(ei + E + base + 4);
        int4 kA = *reinterpret_cast<const int4*>(rank + base);
        int4 kB = *reinterpret_cast<const int4*>(rank + base + 4);
        csr[col_off[cA.x] + kA.x] = rA.x;
        csr[col_off[cA.y] + kA.y] = rA.y;
        csr[col_off[cA.z] + kA.z] = rA.z;
        csr[col_off[cA.w] + kA.w] = rA.w;
        csr[col_off[cB.x] + kB.x] = rB.x;
        csr[col_off[cB.y] + kB.y] = rB.y;
        csr[col_off[cB.z] + kB.z] = rB.z;
        csr[col_off[cB.w] + kB.w] = rB.w;
    } else {
        for (int e = base; e < E; ++e)
            csr[col_off[ei[E + e]] + rank[e]] = ei[e];
    }
}

// ---------------- dense K=64: preload a[K], m-chunks of 4 accs ----------------

template<int K, int M, bool RELU, bool BIAS>
__global__ void dense_small_k(const float* __restrict__ A, const float* __restrict__ W,
                              const float* __restrict__ b, float* __restrict__ out, int n) {
    int v = blockIdx.x * blockDim.x + threadIdx.x;
    if (v >= n) return;
    float a[K];
    const float4* ap = reinterpret_cast<const float4*>(A + (size_t)v * K);
#pragma unroll
    for (int k = 0; k < K / 4; ++k) {
        float4 t = ap[k];
        a[4 * k + 0] = t.x; a[4 * k + 1] = t.y; a[4 * k + 2] = t.z; a[4 * k + 3] = t.w;
    }
    float4* op = reinterpret_cast<float4*>(out + (size_t)v * M);
#pragma unroll 1
    for (int m = 0; m < M; m += 4) {
        float acc0 = BIAS ? b[m + 0] : 0.f;
        float acc1 = BIAS ? b[m + 1] : 0.f;
        float acc2 = BIAS ? b[m + 2] : 0.f;
        float acc3 = BIAS ? b[m + 3] : 0.f;
#pragma unroll
        for (int k = 0; k < K; ++k) {
            float av = a[k];
            acc0 = fmaf(av, W[(m + 0) * K + k], acc0);
            acc1 = fmaf(av, W[(m + 1) * K + k], acc1);
            acc2 = fmaf(av, W[(m + 2) * K + k], acc2);
            acc3 = fmaf(av, W[(m + 3) * K + k], acc3);
        }
        if (RELU) {
            acc0 = fmaxf(acc0, 0.f); acc1 = fmaxf(acc1, 0.f);
            acc2 = fmaxf(acc2, 0.f); acc3 = fmaxf(acc3, 0.f);
        }
        float4 o; o.x = acc0; o.y = acc1; o.z = acc2; o.w = acc3;
        op[m >> 2] = o;
    }
}

// ---------------- encoder (K=128): 2 passes of acc[32], stream A-row each pass ----------------

template<int K, int M, int MC>
__global__ void dense_enc_k(const float* __restrict__ A, const float* __restrict__ W,
                            const float* __restrict__ b, float* __restrict__ out, int n) {
    int v = blockIdx.x * blockDim.x + threadIdx.x;
    if (v >= n) return;
    const float4* ap = reinterpret_cast<const float4*>(A + (size_t)v * K);
    float4* op = reinterpret_cast<float4*>(out + (size_t)v * M);
#pragma unroll 1
    for (int mc = 0; mc < M; mc += MC) {
        float acc[MC];
#pragma unroll
        for (int m = 0; m < MC; ++m) acc[m] = b[mc + m];
#pragma unroll 1
        for (int kb = 0; kb < K / 4; ++kb) {
            float4 a4 = ap[kb];
#pragma unroll
            for (int m = 0; m < MC; ++m) {
                const float* wr = W + (size_t)(mc + m) * K + kb * 4;
                acc[m] = fmaf(a4.x, wr[0], acc[m]);
                acc[m] = fmaf(a4.y, wr[1], acc[m]);
                acc[m] = fmaf(a4.z, wr[2], acc[m]);
                acc[m] = fmaf(a4.w, wr[3], acc[m]);
            }
        }
#pragma unroll
        for (int m = 0; m < MC; m += 4) {
            float4 o;
            o.x = fmaxf(acc[m + 0], 0.f);
            o.y = fmaxf(acc[m + 1], 0.f);
            o.z = fmaxf(acc[m + 2], 0.f);
            o.w = fmaxf(acc[m + 3], 0.f);
            op[(mc + m) >> 2] = o;
        }
    }
}

// ---------------- fused gather: agg (in-edges of v) + gamma scatter ----------------
// wave per node; 4 groups of 16 lanes; 2-deep edge unroll (8 rows in flight/wave)
__global__ void gather_k(const float* __restrict__ X, const int* __restrict__ csr,
                         const int* __restrict__ col_off, const float* __restrict__ dinv,
                         float* __restrict__ pre, float* __restrict__ gs, int n) {
    int v = blockIdx.x * 4 + (threadIdx.x >> 6);
    if (v >= n) return;
    int lane = threadIdx.x & 63;
    int grp = lane >> 4;
    int sub = lane & 15;

    float4 xv = reinterpret_cast<const float4*>(X + (size_t)v * NHID)[sub];
    int beg = col_off[v], end = col_off[v + 1];

    float4 acc = make_float4(0.f, 0.f, 0.f, 0.f);
    int e = beg + grp;
    for (; e + 4 < end; e += 8) {
        int s0 = csr[e];
        int s1 = csr[e + 4];
        float w0 = dinv[s0];
        float w1 = dinv[s1];
        float4 x0 = reinterpret_cast<const float4*>(X + (size_t)s0 * NHID)[sub];
        float4 x1 = reinterpret_cast<const float4*>(X + (size_t)s1 * NHID)[sub];
        acc.x = fmaf(w0, x0.x, acc.x); acc.y = fmaf(w0, x0.y, acc.y);
        acc.z = fmaf(w0, x0.z, acc.z); acc.w = fmaf(w0, x0.w, acc.w);
        acc.x = fmaf(w1, x1.x, acc.x); acc.y = fmaf(w1, x1.y, acc.y);
        acc.z = fmaf(w1, x1.z, acc.z); acc.w = fmaf(w1, x1.w, acc.w);
        float dx = x0.x - xv.x; float p0 = dx * dx;
        dx = x0.y - xv.y; p0 = fmaf(dx, dx, p0);
        dx = x0.z - xv.z; p0 = fmaf(dx, dx, p0);
        dx = x0.w - xv.w; p0 = fmaf(dx, dx, p0);
        dx = x1.x - xv.x; float p1 = dx * dx;
        dx = x1.y - xv.y; p1 = fmaf(dx, dx, p1);
        dx = x1.z - xv.z; p1 = fmaf(dx, dx, p1);
        dx = x1.w - xv.w; p1 = fmaf(dx, dx, p1);
#pragma unroll
        for (int m = 1; m <= 8; m <<= 1) {
            p0 += __shfl_xor(p0, m, 64);
            p1 += __shfl_xor(p1, m, 64);
        }
        if (sub == 0) {
            atomicAdd(&gs[s0], p0);
            atomicAdd(&gs[s1], p1);
        }
    }
    if (e < end) {
        int s = csr[e];
        float w = dinv[s];
        float4 xs = reinterpret_cast<const float4*>(X + (size_t)s * NHID)[sub];
        acc.x = fmaf(w, xs.x, acc.x); acc.y = fmaf(w, xs.y, acc.y);
        acc.z = fmaf(w, xs.z, acc.z); acc.w = fmaf(w, xs.w, acc.w);
        float dx = xs.x - xv.x; float part = dx * dx;
        dx = xs.y - xv.y; part = fmaf(dx, dx, part);
        dx = xs.z - xv.z; part = fmaf(dx, dx, part);
        dx = xs.w - xv.w; part = fmaf(dx, dx, part);
#pragma unroll
        for (int m = 1; m <= 8; m <<= 1) part += __shfl_xor(part, m, 64);
        if (sub == 0) atomicAdd(&gs[s], part);
    }
#pragma unroll
    for (int m = 16; m <= 32; m <<= 1) {
        acc.x += __shfl_xor(acc.x, m, 64);
        acc.y += __shfl_xor(acc.y, m, 64);
        acc.z += __shfl_xor(acc.z, m, 64);
        acc.w += __shfl_xor(acc.w, m, 64);
    }
    if (grp == 0) {
        float dv = dinv[v];
        float dv2 = dv * dv;
        float4 o;
        o.x = fmaf(dv, acc.x, dv2 * xv.x);
        o.y = fmaf(dv, acc.y, dv2 * xv.y);
        o.z = fmaf(dv, acc.z, dv2 * xv.z);
        o.w = fmaf(dv, acc.w, dv2 * xv.w);
        reinterpret_cast<float4*>(pre + (size_t)v * NHID)[sub] = o;
    }
}

// ---------------- fused per-layer epilogue ----------------
// t = relu(pre @ W^T + b); g = tanh(gs/max(outdeg,1));
// X = (X + g*(t + skip)) / (1 + 2g);  gs = 0 for next layer
__global__ void update_k(float* __restrict__ X, const float* __restrict__ pre,
                         const float* __restrict__ skip, const float* __restrict__ W,
                         const float* __restrict__ b, float* __restrict__ gs,
                         const int* __restrict__ cnt_row, int n) {
    int v = blockIdx.x * blockDim.x + threadIdx.x;
    if (v >= n) return;
    float a[NHID];
    const float4* ap = reinterpret_cast<const float4*>(pre + (size_t)v * NHID);
#pragma unroll
    for (int k = 0; k < NHID / 4; ++k) {
        float4 t = ap[k];
        a[4 * k + 0] = t.x; a[4 * k + 1] = t.y; a[4 * k + 2] = t.z; a[4 * k + 3] = t.w;
    }
    float gv = tanhf(gs[v] / fmaxf((float)cnt_row[v], 1.f));
    gs[v] = 0.f;
    float inv = 1.0f / (1.0f + 2.0f * gv);

    float4* Xp = reinterpret_cast<float4*>(X + (size_t)v * NHID);
    const float4* Sp = reinterpret_cast<const float4*>(skip + (size_t)v * NHID);
#pragma unroll 1
    for (int m = 0; m < NHID; m += 4) {
        float t0 = b[m + 0], t1 = b[m + 1], t2 = b[m + 2], t3 = b[m + 3];
#pragma unroll
        for (int k = 0; k < NHID; ++k) {
            float av = a[k];
            t0 = fmaf(av, W[(m + 0) * NHID + k], t0);
            t1 = fmaf(av, W[(m + 1) * NHID + k], t1);
            t2 = fmaf(av, W[(m + 2) * NHID + k], t2);
            t3 = fmaf(av, W[(m + 3) * NHID + k], t3);
        }
        t0 = fmaxf(t0, 0.f); t1 = fmaxf(t1, 0.f);
        t2 = fmaxf(t2, 0.f); t3 = fmaxf(t3, 0.f);
        float4 x4 = Xp[m >> 2];
        float4 s4 = Sp[m >> 2];
        float4 o;
        o.x = (x4.x + gv * (t0 + s4.x)) * inv;
        o.y = (x4.y + gv * (t1 + s4.y)) * inv;
        o.z = (x4.z + gv * (t2 + s4.z)) * inv;
        o.w = (x4.w + gv * (t3 + s4.w)) * inv;
        Xp[m >> 2] = o;
    }
}

// ---------------- launch ----------------

extern "C" void kernel_launch(void* const* d_in, const int* in_sizes, int n_in,
                              void* d_out, int out_size, void* d_ws, size_t ws_size,
                              hipStream_t stream) {
    const float* x      = (const float*)d_in[0];
    const int*   ei     = (const int*)  d_in[1];
    const float* enc_W  = (const float*)d_in[2];
    const float* enc_b  = (const float*)d_in[3];
    const float* conv_W = (const float*)d_in[4];
    const float* conv_b = (const float*)d_in[5];
    const float* W_skip = (const float*)d_in[6];
    const float* dec_W  = (const float*)d_in[7];
    const float* dec_b  = (const float*)d_in[8];

    const int n = in_sizes[0] / NFEAT;
    const int E = in_sizes[1] / 2;

    char* ws = (char*)d_ws;
    auto alloc = [&](size_t bytes) {
        char* p = ws;
        ws += (bytes + 255) & ~(size_t)255;
        return p;
    };

    float* X    = (float*)alloc((size_t)n * NHID * 4);
    float* pre  = (float*)alloc((size_t)n * NHID * 4);
    float* skip = (float*)alloc((size_t)n * NHID * 4);
    float* gs   = (float*)alloc((size_t)n * 4);
    float* dinv = (float*)alloc((size_t)n * 4);
    int* cnt_row = (int*)alloc((size_t)n * 4);
    int* cnt_col = (int*)alloc((size_t)n * 4);
    int* col_off = (int*)alloc((size_t)(n + 1) * 4);
    int* rank    = (int*)alloc((size_t)E * 4);
    int* bsc     = (int*)alloc(1024 * 4);
    int* csr     = (int*)alloc((size_t)E * 4);

    hipMemsetAsync(cnt_row, 0, (size_t)n * 4, stream);
    hipMemsetAsync(cnt_col, 0, (size_t)n * 4, stream);

    count_rank_k<<<(E / 4 + 255) / 256, 256, 0, stream>>>(ei, E, cnt_col, cnt_row, rank);

    int nb = (n + 1023) / 1024;
    scanA_k<<<nb, 1024, 0, stream>>>(cnt_col, col_off, bsc, dinv, n);
    scanB_k<<<1, 1024, 0, stream>>>(bsc, nb);
    scanC_k<<<nb, 1024, 0, stream>>>(col_off, bsc, gs, n, E);
    scatter_k<<<(E / 8 + 255) / 256, 256, 0, stream>>>(ei, E, col_off, rank, csr);

    // encoder: X = relu(x @ enc_W^T + enc_b)
    dense_enc_k<NFEAT, NHID, 32><<<(n + 255) / 256, 256, 0, stream>>>(x, enc_W, enc_b, X, n);
    // skip_val = X_init @ W_skip^T
    dense_small_k<NHID, NHID, false, false><<<(n + 255) / 256, 256, 0, stream>>>(X, W_skip, nullptr, skip, n);

    for (int l = 0; l < NLAYERS; ++l) {
        gather_k<<<(n + 3) / 4, 256, 0, stream>>>(X, csr, col_off, dinv, pre, gs, n);
        update_k<<<(n + 255) / 256, 256, 0, stream>>>(X, pre, skip, conv_W, conv_b, gs, cnt_row, n);
    }

    // decode: out = X @ dec_W^T + dec_b
    dense_small_k<NHID, NCLASS, false, true><<<(n + 255) / 256, 256, 0, stream>>>(X, dec_W, dec_b, (float*)d_out, n);
}